// Round 1
// baseline (2002.171 us; speedup 1.0000x reference)
//
#include <hip/hip_runtime.h>
#include <math.h>

#define B_    32
#define H_    2048
#define V_    128000
#define HIST_ 2048
#define TOPK  50

// ---------------------------------------------------------------- LayerNorm
__global__ __launch_bounds__(256) void ln_kernel(const float* __restrict__ x,
        const float* __restrict__ gamma, const float* __restrict__ beta,
        float* __restrict__ h) {
    int b = blockIdx.x, t = threadIdx.x;
    const float* xr = x + b * H_;
    __shared__ float red[4];
    __shared__ float sval;
    float s = 0.f;
    for (int k = t; k < H_; k += 256) s += xr[k];
    #pragma unroll
    for (int o = 32; o; o >>= 1) s += __shfl_down(s, o);
    if ((t & 63) == 0) red[t >> 6] = s;
    __syncthreads();
    if (t == 0) sval = (red[0] + red[1] + red[2] + red[3]) * (1.f / H_);
    __syncthreads();
    float mu = sval;
    float v = 0.f;
    for (int k = t; k < H_; k += 256) { float d = xr[k] - mu; v += d * d; }
    #pragma unroll
    for (int o = 32; o; o >>= 1) v += __shfl_down(v, o);
    if ((t & 63) == 0) red[t >> 6] = v;
    __syncthreads();
    if (t == 0) sval = 1.f / sqrtf((red[0] + red[1] + red[2] + red[3]) * (1.f / H_) + 1e-5f);
    __syncthreads();
    float rstd = sval;
    for (int k = t; k < H_; k += 256)
        h[b * H_ + k] = (xr[k] - mu) * rstd * gamma[k] + beta[k];
}

// ---------------------------------------------------------------- GEMM
// logits[b][v] = sum_k h[b][k] * W[v][k].  One thread owns one vocab row,
// all 32 batch accumulators in registers.  K-chunked single-LDS-buffer
// pipeline with register prefetch of the next chunk (loads in flight across
// the compute phase).  W tile XOR-swizzled at 16B-granule level so both the
// staging writes and the per-row b128 reads hit the 8-clk LDS floor.
#define VT  256   // vocab rows per block
#define KC  32    // k per chunk
#define NCH (H_ / KC)

__global__ __launch_bounds__(256, 2) void gemm_kernel(const float* __restrict__ Wm,
        const float* __restrict__ hs, float* __restrict__ logits) {
    __shared__ float ldsW[VT * KC];   // 32 KB, swizzled
    __shared__ float ldsH[KC * B_];   // 4 KB, transposed h[k][b]
    const int t  = threadIdx.x;
    const int v0 = blockIdx.x * VT;

    float acc[B_];
    #pragma unroll
    for (int i = 0; i < B_; i++) acc[i] = 0.f;

    float4 wreg[8];
    float4 hreg;
    const int hb = t >> 3, hk = (t & 7) * 4;

    // preload chunk 0
    #pragma unroll
    for (int i = 0; i < 8; i++) {
        int g = i * 256 + t, r = g >> 3, p = g & 7;
        wreg[i] = *(const float4*)(Wm + (size_t)(v0 + r) * H_ + p * 4);
    }
    hreg = *(const float4*)(hs + hb * H_ + hk);

    for (int c = 0; c < NCH; c++) {
        // stage chunk c into LDS
        #pragma unroll
        for (int i = 0; i < 8; i++) {
            int g = i * 256 + t, r = g >> 3, p = g & 7;
            *(float4*)&ldsW[r * KC + ((p ^ (r & 7)) << 2)] = wreg[i];
        }
        ldsH[(hk + 0) * B_ + hb] = hreg.x;
        ldsH[(hk + 1) * B_ + hb] = hreg.y;
        ldsH[(hk + 2) * B_ + hb] = hreg.z;
        ldsH[(hk + 3) * B_ + hb] = hreg.w;
        __syncthreads();

        // issue prefetch of chunk c+1 (consumed by next iteration's ds_write)
        if (c + 1 < NCH) {
            int kn = (c + 1) * KC;
            #pragma unroll
            for (int i = 0; i < 8; i++) {
                int g = i * 256 + t, r = g >> 3, p = g & 7;
                wreg[i] = *(const float4*)(Wm + (size_t)(v0 + r) * H_ + kn + p * 4);
            }
            hreg = *(const float4*)(hs + hb * H_ + kn + hk);
        }

        // compute chunk c
        for (int q = 0; q < KC / 4; q++) {
            float4 w4 = *(const float4*)&ldsW[t * KC + ((q ^ (t & 7)) << 2)];
            float wk[4] = {w4.x, w4.y, w4.z, w4.w};
            #pragma unroll
            for (int j = 0; j < 4; j++) {
                const float4* hp = (const float4*)&ldsH[(q * 4 + j) * B_];
                #pragma unroll
                for (int g2 = 0; g2 < 8; g2++) {
                    float4 hv = hp[g2];                     // uniform b128: b = 4*g2..+3
                    acc[g2 * 4 + 0] += wk[j] * hv.x;
                    acc[g2 * 4 + 1] += wk[j] * hv.y;
                    acc[g2 * 4 + 2] += wk[j] * hv.z;
                    acc[g2 * 4 + 3] += wk[j] * hv.w;
                }
            }
        }
        __syncthreads();
    }

    const int v = v0 + t;
    #pragma unroll
    for (int b = 0; b < B_; b++)
        logits[(size_t)b * V_ + v] = acc[b];   // consecutive t -> coalesced
}

// ------------------------------------------------------- repetition penalty
// Two kernels: gather+penalize from ORIGINAL logits, then scatter.  A fused
// RMW would double-penalize duplicate ids within a row; the scatter of
// identical values for duplicates is benign.
__global__ __launch_bounds__(256) void pen_gather(const int* __restrict__ ids,
        const float* __restrict__ logits, float* __restrict__ pen) {
    int i = blockIdx.x * 256 + threadIdx.x;   // < 32*2048
    int b = i >> 11;
    int id = ids[i];
    float g = logits[(size_t)b * V_ + id];
    pen[i] = (g < 0.f) ? g * 1.1f : g / 1.1f;
}
__global__ __launch_bounds__(256) void pen_scatter(const int* __restrict__ ids,
        float* __restrict__ logits, const float* __restrict__ pen) {
    int i = blockIdx.x * 256 + threadIdx.x;
    int b = i >> 11;
    logits[(size_t)b * V_ + ids[i]] = pen[i];
}

// ---------------------------------------------------------------- top-k/top-p
__device__ __forceinline__ unsigned f2k(float f) {
    unsigned u = __float_as_uint(f);
    return (u >> 31) ? ~u : (u | 0x80000000u);   // larger float -> larger key
}
__device__ __forceinline__ float k2f(unsigned k) {
    return __uint_as_float((k >> 31) ? (k ^ 0x80000000u) : ~k);
}

__global__ __launch_bounds__(256) void topk_kernel(const float* __restrict__ logits,
        float* __restrict__ out) {
    int b = blockIdx.x, t = threadIdx.x;
    const float* row = logits + (size_t)b * V_;
    __shared__ int hist[256];
    __shared__ int sB1, sC1, sB2, sNa, sNe;
    __shared__ unsigned gtK[64];  __shared__ int gtI[64];
    __shared__ unsigned eqK[256]; __shared__ int eqI[256];
    __shared__ float outv[TOPK];  __shared__ int outi[TOPK];

    // pass 1: histogram of top 8 key bits
    hist[t] = 0;
    __syncthreads();
    for (int v = t; v < V_; v += 256) atomicAdd(&hist[f2k(row[v]) >> 24], 1);
    __syncthreads();
    if (t == 0) {
        int c = 0, i = 255;
        for (; i >= 0; i--) { if (c + hist[i] >= TOPK) break; c += hist[i]; }
        sB1 = i; sC1 = c;
    }
    __syncthreads();
    unsigned b1 = (unsigned)sB1; int c1 = sC1;

    // pass 2: next 8 bits within bin b1
    hist[t] = 0;
    __syncthreads();
    for (int v = t; v < V_; v += 256) {
        unsigned k = f2k(row[v]);
        if ((k >> 24) == b1) atomicAdd(&hist[(k >> 16) & 255], 1);
    }
    __syncthreads();
    if (t == 0) {
        int c = c1, i = 255;
        for (; i >= 0; i--) { if (c + hist[i] >= TOPK) break; c += hist[i]; }
        sB2 = i; sNa = 0; sNe = 0;
    }
    __syncthreads();
    unsigned pref = (b1 << 8) | (unsigned)sB2;

    // pass 3: collect strict-top list (<=49 by construction) and boundary list
    for (int v = t; v < V_; v += 256) {
        unsigned k = f2k(row[v]);
        unsigned t16 = k >> 16;
        if (t16 > pref)       { int p = atomicAdd(&sNa, 1); if (p < 64)  { gtK[p] = k; gtI[p] = v; } }
        else if (t16 == pref) { int p = atomicAdd(&sNe, 1); if (p < 256) { eqK[p] = k; eqI[p] = v; } }
    }
    __syncthreads();

    if (t == 0) {
        int na = sNa; if (na > TOPK) na = TOPK;
        // sort strict-top by (key desc, idx asc) — matches lax.top_k stable order
        for (int i = 1; i < na; i++) {
            unsigned k = gtK[i]; int id = gtI[i]; int j = i - 1;
            for (; j >= 0 && (gtK[j] < k || (gtK[j] == k && gtI[j] > id)); j--) {
                gtK[j + 1] = gtK[j]; gtI[j + 1] = gtI[j];
            }
            gtK[j + 1] = k; gtI[j + 1] = id;
        }
        for (int i = 0; i < na; i++) { outv[i] = k2f(gtK[i]); outi[i] = gtI[i]; }
        // fill remaining slots from boundary bin by (key desc, idx asc)
        int ne = sNe; if (ne > 256) ne = 256;
        for (int s = na; s < TOPK; s++) {
            int best = -1; unsigned bk = 0; int bi = 0x7fffffff;
            for (int i = 0; i < ne; i++) {
                if (eqI[i] < 0) continue;
                if (best < 0 || eqK[i] > bk || (eqK[i] == bk && eqI[i] < bi)) {
                    best = i; bk = eqK[i]; bi = eqI[i];
                }
            }
            outv[s] = k2f(bk); outi[s] = bi; eqI[best] = -1;
        }
    }
    __syncthreads();

    // softmax -> inclusive cumsum -> top-p mask -> softmax, wave-parallel
    if (t < 64) {
        int i = t;
        float m  = outv[0];                                  // sorted desc
        float vi = (i < TOPK) ? outv[i] : 0.f;
        float e  = (i < TOPK) ? expf(vi - m) : 0.f;
        float tot = e;
        #pragma unroll
        for (int o = 1; o < 64; o <<= 1) tot += __shfl_xor(tot, o);
        float p = e / tot;
        float pre = p;                                       // inclusive prefix
        #pragma unroll
        for (int o = 1; o < 64; o <<= 1) { float u = __shfl_up(pre, o); if (t >= o) pre += u; }
        bool keep = (pre < 0.8f) || (i < 5);
        float f  = keep ? vi : -1000.f;
        float e2 = (i < TOPK) ? expf(f - m) : 0.f;
        float tot2 = e2;
        #pragma unroll
        for (int o = 1; o < 64; o <<= 1) tot2 += __shfl_xor(tot2, o);
        if (i < TOPK) {
            out[b * TOPK + i] = e2 / tot2;                   // probs
            out[B_ * TOPK + b * TOPK + i] = (float)outi[i];  // tokens as f32
        }
    }
}

// ---------------------------------------------------------------- launch
extern "C" void kernel_launch(void* const* d_in, const int* in_sizes, int n_in,
                              void* d_out, int out_size, void* d_ws, size_t ws_size,
                              hipStream_t stream) {
    const int*   ids    = (const int*)d_in[0];     // input_ids [32,2048]
    const float* hidden = (const float*)d_in[1];   // [32,2048]
    const float* gamma  = (const float*)d_in[2];   // [2048]
    const float* beta   = (const float*)d_in[3];   // [2048]
    const float* Wm     = (const float*)d_in[4];   // [128000,2048]
    float* out = (float*)d_out;

    // workspace layout: h (256KB) | logits (16MB) | pen (256KB) ~= 16.9 MB
    char* ws = (char*)d_ws;
    float* h      = (float*)ws;
    float* logits = (float*)(ws + 262144);
    float* pen    = (float*)(ws + 262144 + 16384000);

    ln_kernel  <<<B_,        256, 0, stream>>>(hidden, gamma, beta, h);
    gemm_kernel<<<V_ / VT,   256, 0, stream>>>(Wm, h, logits);
    pen_gather <<<(B_*HIST_)/256, 256, 0, stream>>>(ids, logits, pen);
    pen_scatter<<<(B_*HIST_)/256, 256, 0, stream>>>(ids, logits, pen);
    topk_kernel<<<B_,        256, 0, stream>>>(logits, out);
}